// Round 1
// baseline (172.432 us; speedup 1.0000x reference)
//
#include <hip/hip_runtime.h>

#define HW   16384
#define CH   256
#define WD   128
#define BB   4
#define NPTS 4

typedef _Float16 half8 __attribute__((ext_vector_type(8)));
typedef float    f32x4 __attribute__((ext_vector_type(4)));

// ---- workspace layout (bytes) ----
#define WS_XT   0ull                    // _Float16 [65536][256]   (32 MB)
#define WS_QKV  33554432ull             // _Float16 [65536][768]   (96 MB)
#define WS_WB   134217728ull            // _Float16 [768][256]     (384 KB)
#define WS_WOQ  134610944ull             // float   [256][8]       (8 KB)
#define WS_BOF  134619136ull            // float    [8]
#define WS_BALL 134619200ull            // float    [768]  qkv bias
#define WS_IDX  134622272ull            // int      [4][4][16384]  (1 MB)

// ---------- weight prep: concat(Wq,Wk,Wv) -> fp16 [768][256]; bias_all f32 [768] ----------
__global__ void k_wb(const float* __restrict__ Wq, const float* __restrict__ Wk,
                     const float* __restrict__ Wv, const float* __restrict__ bq,
                     const float* __restrict__ bk, const float* __restrict__ bv,
                     _Float16* __restrict__ wb, float* __restrict__ ball) {
    int r = blockIdx.x;           // 0..767
    int c = threadIdx.x;          // 0..255
    const float* src; const float* bsrc; int rr;
    if (r < 256)      { src = Wq; bsrc = bq; rr = r; }
    else if (r < 512) { src = Wk; bsrc = bk; rr = r - 256; }
    else              { src = Wv; bsrc = bv; rr = r - 512; }
    wb[(size_t)r * 256 + c] = (_Float16)src[(size_t)rr * 256 + c];
    if (c == 0) ball[r] = bsrc[rr];
}

// ---------- fused offset weights: Woq = Wo@Wq (fp32), bof = bo + Wo@bq ----------
__global__ void k_woq(const float* __restrict__ Wo, const float* __restrict__ Wq,
                      const float* __restrict__ bq, const float* __restrict__ bo,
                      float* __restrict__ woq, float* __restrict__ bof) {
    int j = blockIdx.x;           // 0..7
    int c = threadIdx.x;          // 0..255
    float s = 0.f;
    for (int o = 0; o < 256; o++) s += Wo[j * 256 + o] * Wq[o * 256 + c];
    woq[c * 8 + j] = s;
    if (c == 0) {
        float t = bo[j];
        for (int o = 0; o < 256; o++) t += Wo[j * 256 + o] * bq[o];
        bof[j] = t;
    }
}

// ---------- x [b][c][p] f32  ->  xt [b*HW+p][c] fp16 ----------
__global__ void k_transpose(const float* __restrict__ x, _Float16* __restrict__ xt) {
    __shared__ _Float16 tile[32][33];
    int p0 = blockIdx.x * 32, c0 = blockIdx.y * 32, b = blockIdx.z;
    const float* xb = x + (size_t)b * CH * HW;
    #pragma unroll
    for (int i = 0; i < 4; i++) {
        int c = c0 + threadIdx.y + i * 8;
        tile[threadIdx.y + i * 8][threadIdx.x] = (_Float16)xb[(size_t)c * HW + p0 + threadIdx.x];
    }
    __syncthreads();
    #pragma unroll
    for (int i = 0; i < 4; i++) {
        int p = p0 + threadIdx.y + i * 8;
        xt[((size_t)(b * HW + p)) * 256 + c0 + threadIdx.x] = tile[threadIdx.x][threadIdx.y + i * 8];
    }
}

// ---------- fp32 offsets -> gather indices (discontinuous path, keep fp32) ----------
__global__ void k_offsets(const float* __restrict__ x, const float* __restrict__ woq,
                          const float* __restrict__ bof, int* __restrict__ idxb) {
    __shared__ float wl[256 * 8];
    __shared__ float bl[8];
    int tid = threadIdx.x;
    for (int i = tid; i < 256 * 8; i += 256) wl[i] = woq[i];
    if (tid < 8) bl[tid] = bof[tid];
    __syncthreads();
    int b = blockIdx.y;
    int p = blockIdx.x * 256 + tid;
    const float* xb = x + (size_t)b * CH * HW + p;
    float acc[8];
    #pragma unroll
    for (int j = 0; j < 8; j++) acc[j] = bl[j];
    for (int c = 0; c < 256; c++) {
        float xv = xb[(size_t)c * HW];
        #pragma unroll
        for (int j = 0; j < 8; j++) acc[j] += wl[c * 8 + j] * xv;
    }
    int h = p >> 7, w = p & 127;
    #pragma unroll
    for (int n = 0; n < 4; n++) {
        float rw = fminf(fmaxf((float)w + acc[2 * n],     0.f), 127.f);
        float rh = fminf(fmaxf((float)h + acc[2 * n + 1], 0.f), 127.f);
        idxb[(b * NPTS + n) * HW + p] = ((int)rh) * WD + (int)rw;
    }
}

// ---------- MFMA fp16 GEMM + bias: qkv[m][n] = sum_k xt[m][k]*wb[n][k] + ball[n] ----------
__launch_bounds__(256)
__global__ void k_gemm(const _Float16* __restrict__ xt, const _Float16* __restrict__ wb,
                       const float* __restrict__ ball, _Float16* __restrict__ qkv) {
    __shared__ _Float16 As[128 * 32];
    __shared__ _Float16 Bs[128 * 32];
    int tid = threadIdx.x;
    int m0 = blockIdx.y * 128;
    int n0 = blockIdx.x * 128;
    int lane = tid & 63, wid = tid >> 6;
    int wr = wid >> 1, wc = wid & 1;
    int g = lane >> 4, r = lane & 15;

    int ar = tid >> 2, aseg = tid & 3;
    int sw = aseg ^ ((ar >> 1) & 3);

    f32x4 acc[4][4] = {};

    for (int kt = 0; kt < 8; kt++) {
        int k0 = kt * 32;
        uint4 a0 = *(const uint4*)(xt + ((size_t)(m0 + ar))      * 256 + k0 + aseg * 8);
        uint4 a1 = *(const uint4*)(xt + ((size_t)(m0 + 64 + ar)) * 256 + k0 + aseg * 8);
        uint4 b0 = *(const uint4*)(wb + ((size_t)(n0 + ar))      * 256 + k0 + aseg * 8);
        uint4 b1 = *(const uint4*)(wb + ((size_t)(n0 + 64 + ar)) * 256 + k0 + aseg * 8);
        __syncthreads();
        *(uint4*)(As + ar * 32 + sw * 8)        = a0;
        *(uint4*)(As + (64 + ar) * 32 + sw * 8) = a1;
        *(uint4*)(Bs + ar * 32 + sw * 8)        = b0;
        *(uint4*)(Bs + (64 + ar) * 32 + sw * 8) = b1;
        __syncthreads();

        half8 af[4], bf[4];
        #pragma unroll
        for (int mb = 0; mb < 4; mb++) {
            int row = wr * 64 + mb * 16 + r;
            int slot = g ^ ((row >> 1) & 3);
            af[mb] = *(const half8*)(As + row * 32 + slot * 8);
        }
        #pragma unroll
        for (int nb = 0; nb < 4; nb++) {
            int row = wc * 64 + nb * 16 + r;
            int slot = g ^ ((row >> 1) & 3);
            bf[nb] = *(const half8*)(Bs + row * 32 + slot * 8);
        }
        #pragma unroll
        for (int mb = 0; mb < 4; mb++)
            #pragma unroll
            for (int nb = 0; nb < 4; nb++)
                acc[mb][nb] = __builtin_amdgcn_mfma_f32_16x16x32_f16(af[mb], bf[nb], acc[mb][nb], 0, 0, 0);
    }

    // C/D layout (HW-verified): col = lane&15, row = (lane>>4)*4 + reg
    #pragma unroll
    for (int nb = 0; nb < 4; nb++) {
        int n = n0 + wc * 64 + nb * 16 + (lane & 15);
        float bn = ball[n];
        #pragma unroll
        for (int mb = 0; mb < 4; mb++)
            #pragma unroll
            for (int reg = 0; reg < 4; reg++) {
                int m = m0 + wr * 64 + mb * 16 + (lane >> 4) * 4 + reg;
                qkv[(size_t)m * 768 + n] = (_Float16)(acc[mb][nb][reg] + bn);
            }
    }
}

// ---------- gather + attention ----------
__launch_bounds__(256)
__global__ void k_attn(const _Float16* __restrict__ qkv, const int* __restrict__ idxb,
                       float* __restrict__ out) {
    __shared__ float attn_s[64][4];
    __shared__ int   idx_s[4][64];
    int tid = threadIdx.x;
    int b = blockIdx.y;
    int p0 = blockIdx.x * 64;

    {
        int pl = tid >> 2, n = tid & 3;
        int p = p0 + pl;
        int my_idx = idxb[(b * NPTS + n) * HW + p];
        const half8* qrow = (const half8*)(qkv + ((size_t)(b * HW + p)) * 768);
        const half8* krow = (const half8*)(qkv + ((size_t)(b * HW + my_idx)) * 768 + 256);
        float acc = 0.f;
        #pragma unroll 8
        for (int j = 0; j < 32; j++) {
            half8 q8 = qrow[j], k8 = krow[j];
            #pragma unroll
            for (int e = 0; e < 8; e++) acc += (float)q8[e] * (float)k8[e];
        }
        attn_s[pl][n] = acc;
        idx_s[n][pl]  = my_idx;
    }
    __syncthreads();

    {
        int w = tid >> 6, lane = tid & 63;
        int p = p0 + lane;
        int cb = w * 64;
        float o[64];
        #pragma unroll
        for (int i = 0; i < 64; i++) o[i] = 0.f;
        #pragma unroll
        for (int nn = 0; nn < 4; nn++) {
            float a = attn_s[lane][nn];
            const half8* vrow = (const half8*)(qkv + ((size_t)(b * HW + idx_s[nn][lane])) * 768 + 512 + cb);
            #pragma unroll
            for (int j = 0; j < 8; j++) {
                half8 v8 = vrow[j];
                #pragma unroll
                for (int e = 0; e < 8; e++) o[j * 8 + e] += a * (float)v8[e];
            }
        }
        float* ob = out + (size_t)b * CH * HW + p;
        #pragma unroll
        for (int ci = 0; ci < 64; ci++) ob[(size_t)(cb + ci) * HW] = o[ci];
    }
}

extern "C" void kernel_launch(void* const* d_in, const int* in_sizes, int n_in,
                              void* d_out, int out_size, void* d_ws, size_t ws_size,
                              hipStream_t stream) {
    const float* x  = (const float*)d_in[0];
    const float* Wq = (const float*)d_in[1];
    const float* bq = (const float*)d_in[2];
    const float* Wk = (const float*)d_in[3];
    const float* bk = (const float*)d_in[4];
    const float* Wv = (const float*)d_in[5];
    const float* bv = (const float*)d_in[6];
    const float* Wo = (const float*)d_in[7];
    const float* bo = (const float*)d_in[8];
    (void)in_sizes; (void)n_in; (void)out_size; (void)ws_size;

    char* ws = (char*)d_ws;
    _Float16* xt   = (_Float16*)(ws + WS_XT);
    _Float16* qkv  = (_Float16*)(ws + WS_QKV);
    _Float16* wbp  = (_Float16*)(ws + WS_WB);
    float*    woq  = (float*)(ws + WS_WOQ);
    float*    bof  = (float*)(ws + WS_BOF);
    float*    ball = (float*)(ws + WS_BALL);
    int*      idxb = (int*)(ws + WS_IDX);

    k_wb<<<768, 256, 0, stream>>>(Wq, Wk, Wv, bq, bk, bv, wbp, ball);
    k_woq<<<8, 256, 0, stream>>>(Wo, Wq, bq, bo, woq, bof);
    k_transpose<<<dim3(512, 8, 4), dim3(32, 8), 0, stream>>>(x, xt);
    k_offsets<<<dim3(64, 4), 256, 0, stream>>>(x, woq, bof, idxb);
    k_gemm<<<dim3(6, 512), 256, 0, stream>>>(xt, wbp, ball, qkv);
    k_attn<<<dim3(256, 4), 256, 0, stream>>>(qkv, idxb, (float*)d_out);
}

// Round 2
// 152.870 us; speedup vs baseline: 1.1280x; 1.1280x over previous
//
#include <hip/hip_runtime.h>

#define HW   16384
#define CH   256
#define WD   128
#define BB   4
#define NPTS 4

typedef _Float16 half8 __attribute__((ext_vector_type(8)));
typedef _Float16 half4 __attribute__((ext_vector_type(4)));
typedef float    f32x4 __attribute__((ext_vector_type(4)));

// ---- workspace layout (bytes) ----
#define WS_XT   0ull                    // _Float16 [65536][256]   (32 MB)
#define WS_QKV  33554432ull             // _Float16 [65536][768]   (96 MB)
#define WS_WB   134217728ull            // _Float16 [768][256]     (384 KB)
#define WS_WOQ  134610944ull            // float    [256][8]       (8 KB)
#define WS_BOF  134619136ull            // float    [8]
#define WS_BALL 134619200ull            // float    [768]
#define WS_IDX  134622272ull            // int      [4][4][16384]  (1 MB)

// ---------- weight prep: concat(Wq,Wk,Wv) -> fp16 [768][256]; bias_all f32 [768] ----------
__global__ void k_wb(const float* __restrict__ Wq, const float* __restrict__ Wk,
                     const float* __restrict__ Wv, const float* __restrict__ bq,
                     const float* __restrict__ bk, const float* __restrict__ bv,
                     _Float16* __restrict__ wb, float* __restrict__ ball) {
    int r = blockIdx.x;           // 0..767
    int c = threadIdx.x;          // 0..255
    const float* src; const float* bsrc; int rr;
    if (r < 256)      { src = Wq; bsrc = bq; rr = r; }
    else if (r < 512) { src = Wk; bsrc = bk; rr = r - 256; }
    else              { src = Wv; bsrc = bv; rr = r - 512; }
    wb[(size_t)r * 256 + c] = (_Float16)src[(size_t)rr * 256 + c];
    if (c == 0) ball[r] = bsrc[rr];
}

// ---------- fused offset weights: Woq = Wo@Wq (fp32), bof = bo + Wo@bq ----------
__global__ void k_woq(const float* __restrict__ Wo, const float* __restrict__ Wq,
                      const float* __restrict__ bq, const float* __restrict__ bo,
                      float* __restrict__ woq, float* __restrict__ bof) {
    int j = blockIdx.x;           // 0..7
    int c = threadIdx.x;          // 0..255
    float s = 0.f;
    for (int o = 0; o < 256; o++) s += Wo[j * 256 + o] * Wq[o * 256 + c];
    woq[c * 8 + j] = s;
    if (c == 0) {
        float t = bo[j];
        for (int o = 0; o < 256; o++) t += Wo[j * 256 + o] * bq[o];
        bof[j] = t;
    }
}

// ---------- fused: x[b][c][p] f32 -> xt[b*HW+p][c] fp16  AND  fp32 offsets -> idx ----------
// One read of x. Offsets stay pure fp32 (discontinuous trunc path).
// grid (HW/64, B), block 256 = 4 waves; wave w owns channel slab [w*64, w*64+64).
__launch_bounds__(256)
__global__ void k_prep(const float* __restrict__ x, const float* __restrict__ woq,
                       const float* __restrict__ bof,
                       _Float16* __restrict__ xt, int* __restrict__ idxb) {
    __shared__ float    wl[256 * 8];        // 8 KB
    __shared__ float    bl8[8];
    __shared__ _Float16 tile[64][280];      // 35 KB, pitch 280h=560B -> 560%128=48: all 8 slots hit
    __shared__ float    red[4][64][8];      // 8 KB

    int t = threadIdx.x;
    for (int i = t; i < 256 * 8; i += 256) wl[i] = woq[i];
    if (t < 8) bl8[t] = bof[t];
    __syncthreads();

    int b = blockIdx.y;
    int p0 = blockIdx.x * 64;
    int pl = t & 63, cg = t >> 6;           // lane-pixel, channel-group (per wave)
    const float* xb = x + (size_t)b * CH * HW + p0 + pl;

    float acc[8];
    #pragma unroll
    for (int j = 0; j < 8; j++) acc[j] = 0.f;

    for (int i0 = 0; i0 < 64; i0 += 8) {
        half8 hv;
        #pragma unroll
        for (int i = 0; i < 8; i++) {
            int c = cg * 64 + i0 + i;
            float xv = xb[(size_t)c * HW];
            hv[i] = (_Float16)xv;
            #pragma unroll
            for (int j = 0; j < 8; j++) acc[j] += wl[c * 8 + j] * xv;
        }
        *(half8*)(&tile[pl][cg * 64 + i0]) = hv;
    }
    #pragma unroll
    for (int j = 0; j < 8; j++) red[cg][pl][j] = acc[j];
    __syncthreads();

    // idx: wave n owns sample-point n; lanes = pixels (coalesced idx store)
    {
        int n = cg, p = p0 + pl;
        float sw_ = bl8[2 * n]     + red[0][pl][2 * n]     + red[1][pl][2 * n]
                                   + red[2][pl][2 * n]     + red[3][pl][2 * n];
        float sh_ = bl8[2 * n + 1] + red[0][pl][2 * n + 1] + red[1][pl][2 * n + 1]
                                   + red[2][pl][2 * n + 1] + red[3][pl][2 * n + 1];
        int h = p >> 7, w = p & 127;
        float rw = fminf(fmaxf((float)w + sw_, 0.f), 127.f);
        float rh = fminf(fmaxf((float)h + sh_, 0.f), 127.f);
        idxb[(b * NPTS + n) * HW + p] = ((int)rh) * WD + (int)rw;
    }

    // transposed xt write: 4 threads/row, 8x uint4 each (64B contiguous per 4 lanes)
    {
        int row = t >> 2;
        size_t gbase = ((size_t)(b * HW + p0 + row)) * 256;
        #pragma unroll
        for (int s = 0; s < 8; s++) {
            int seg = (t & 3) + s * 4;
            *(uint4*)(xt + gbase + seg * 8) = *(const uint4*)(&tile[row][seg * 8]);
        }
    }
}

// ---------- MFMA fp16 GEMM + bias: qkv[m][n] = sum_k xt[m][k]*wb[n][k] + ball[n] ----------
// 128x128 tile, BK=32, 256 thr. XCD-grouped swizzle; swapped-operand MFMA -> packed 8B stores.
__launch_bounds__(256)
__global__ void k_gemm(const _Float16* __restrict__ xt, const _Float16* __restrict__ wb,
                       const float* __restrict__ ball, _Float16* __restrict__ qkv) {
    __shared__ _Float16 As[128 * 32];
    __shared__ _Float16 Bs[128 * 32];
    int tid = threadIdx.x;

    // bijective XCD swizzle: 3072 blocks = 8 XCD * 384; 6 consecutive logicals share one A-tile
    int bid = blockIdx.x;
    int logical = (bid & 7) * 384 + (bid >> 3);
    int nt = logical % 6, mt = logical / 6;
    int m0 = mt * 128, n0 = nt * 128;

    int lane = tid & 63, wid = tid >> 6;
    int wr = wid >> 1, wc = wid & 1;
    int g = lane >> 4, r = lane & 15;

    int ar = tid >> 2, aseg = tid & 3;
    int sw = aseg ^ ((ar >> 1) & 3);

    f32x4 acc[4][4] = {};

    for (int kt = 0; kt < 8; kt++) {
        int k0 = kt * 32;
        uint4 a0 = *(const uint4*)(xt + ((size_t)(m0 + ar))      * 256 + k0 + aseg * 8);
        uint4 a1 = *(const uint4*)(xt + ((size_t)(m0 + 64 + ar)) * 256 + k0 + aseg * 8);
        uint4 b0 = *(const uint4*)(wb + ((size_t)(n0 + ar))      * 256 + k0 + aseg * 8);
        uint4 b1 = *(const uint4*)(wb + ((size_t)(n0 + 64 + ar)) * 256 + k0 + aseg * 8);
        __syncthreads();
        *(uint4*)(As + ar * 32 + sw * 8)        = a0;
        *(uint4*)(As + (64 + ar) * 32 + sw * 8) = a1;
        *(uint4*)(Bs + ar * 32 + sw * 8)        = b0;
        *(uint4*)(Bs + (64 + ar) * 32 + sw * 8) = b1;
        __syncthreads();

        half8 af[4], bf[4];
        #pragma unroll
        for (int mb = 0; mb < 4; mb++) {
            int row = wr * 64 + mb * 16 + r;
            int slot = g ^ ((row >> 1) & 3);
            af[mb] = *(const half8*)(As + row * 32 + slot * 8);
        }
        #pragma unroll
        for (int nb = 0; nb < 4; nb++) {
            int row = wc * 64 + nb * 16 + r;
            int slot = g ^ ((row >> 1) & 3);
            bf[nb] = *(const half8*)(Bs + row * 32 + slot * 8);
        }
        // swapped operands: D[b_row=n][a_row=m]; lane regs hold 4 consecutive n
        #pragma unroll
        for (int mb = 0; mb < 4; mb++)
            #pragma unroll
            for (int nb = 0; nb < 4; nb++)
                acc[mb][nb] = __builtin_amdgcn_mfma_f32_16x16x32_f16(bf[nb], af[mb], acc[mb][nb], 0, 0, 0);
    }

    // epilogue: m = ...+r (lane&15), n = ...+g*4+reg -> pack 4 fp16 = 8B store
    #pragma unroll
    for (int mb = 0; mb < 4; mb++) {
        int m = m0 + wr * 64 + mb * 16 + r;
        #pragma unroll
        for (int nb = 0; nb < 4; nb++) {
            int nbase = n0 + wc * 64 + nb * 16 + g * 4;
            f32x4 bb = *(const f32x4*)(ball + nbase);
            half4 h;
            #pragma unroll
            for (int i = 0; i < 4; i++) h[i] = (_Float16)(acc[mb][nb][i] + bb[i]);
            *(half4*)(qkv + (size_t)m * 768 + nbase) = h;
        }
    }
}

// ---------- gather + attention ----------
__launch_bounds__(256)
__global__ void k_attn(const _Float16* __restrict__ qkv, const int* __restrict__ idxb,
                       float* __restrict__ out) {
    __shared__ float attn_s[64][4];
    __shared__ int   idx_s[4][64];
    int tid = threadIdx.x;
    int b = blockIdx.y;
    int p0 = blockIdx.x * 64;

    {
        int pl = tid >> 2, n = tid & 3;
        int p = p0 + pl;
        int my_idx = idxb[(b * NPTS + n) * HW + p];
        const half8* qrow = (const half8*)(qkv + ((size_t)(b * HW + p)) * 768);
        const half8* krow = (const half8*)(qkv + ((size_t)(b * HW + my_idx)) * 768 + 256);
        float acc = 0.f;
        #pragma unroll 8
        for (int j = 0; j < 32; j++) {
            half8 q8 = qrow[j], k8 = krow[j];
            #pragma unroll
            for (int e = 0; e < 8; e++) acc += (float)q8[e] * (float)k8[e];
        }
        attn_s[pl][n] = acc;
        idx_s[n][pl]  = my_idx;
    }
    __syncthreads();

    {
        int w = tid >> 6, lane = tid & 63;
        int p = p0 + lane;
        int cb = w * 64;
        float o[64];
        #pragma unroll
        for (int i = 0; i < 64; i++) o[i] = 0.f;
        #pragma unroll
        for (int nn = 0; nn < 4; nn++) {
            float a = attn_s[lane][nn];
            const half8* vrow = (const half8*)(qkv + ((size_t)(b * HW + idx_s[nn][lane])) * 768 + 512 + cb);
            #pragma unroll
            for (int j = 0; j < 8; j++) {
                half8 v8 = vrow[j];
                #pragma unroll
                for (int e = 0; e < 8; e++) o[j * 8 + e] += a * (float)v8[e];
            }
        }
        float* ob = out + (size_t)b * CH * HW + p;
        #pragma unroll
        for (int ci = 0; ci < 64; ci++) ob[(size_t)(cb + ci) * HW] = o[ci];
    }
}

extern "C" void kernel_launch(void* const* d_in, const int* in_sizes, int n_in,
                              void* d_out, int out_size, void* d_ws, size_t ws_size,
                              hipStream_t stream) {
    const float* x  = (const float*)d_in[0];
    const float* Wq = (const float*)d_in[1];
    const float* bq = (const float*)d_in[2];
    const float* Wk = (const float*)d_in[3];
    const float* bk = (const float*)d_in[4];
    const float* Wv = (const float*)d_in[5];
    const float* bv = (const float*)d_in[6];
    const float* Wo = (const float*)d_in[7];
    const float* bo = (const float*)d_in[8];
    (void)in_sizes; (void)n_in; (void)out_size; (void)ws_size;

    char* ws = (char*)d_ws;
    _Float16* xt   = (_Float16*)(ws + WS_XT);
    _Float16* qkv  = (_Float16*)(ws + WS_QKV);
    _Float16* wbp  = (_Float16*)(ws + WS_WB);
    float*    woq  = (float*)(ws + WS_WOQ);
    float*    bof  = (float*)(ws + WS_BOF);
    float*    ball = (float*)(ws + WS_BALL);
    int*      idxb = (int*)(ws + WS_IDX);

    k_wb<<<768, 256, 0, stream>>>(Wq, Wk, Wv, bq, bk, bv, wbp, ball);
    k_woq<<<8, 256, 0, stream>>>(Wo, Wq, bq, bo, woq, bof);
    k_prep<<<dim3(256, 4), 256, 0, stream>>>(x, woq, bof, xt, idxb);
    k_gemm<<<3072, 256, 0, stream>>>(xt, wbp, ball, qkv);
    k_attn<<<dim3(256, 4), 256, 0, stream>>>(qkv, idxb, (float*)d_out);
}